// Round 2
// baseline (607.480 us; speedup 1.0000x reference)
//
#include <hip/hip_runtime.h>
#include <hip/hip_bf16.h>

#define Nn 8192
#define Ee 8192
#define Hh 256

typedef __hip_bfloat16 bf16;

__device__ __forceinline__ float b2f(bf16 v) { return __bfloat162float(v); }
__device__ __forceinline__ float us2f(unsigned int u16) {
    union { unsigned int i; float f; } c;
    c.i = u16 << 16;
    return c.f;
}
// dtype-flexible scalar load: isf32 ? float : bf16
__device__ __forceinline__ float ld(const void* p, int i, int isf32) {
    return isf32 ? ((const float*)p)[i] : b2f(((const bf16*)p)[i]);
}

// Kernel 0: probe dtype of float tensors via adj's binary structure.
// f32 adj => every dword is 0x00000000 or 0x3F800000.
// bf16 adj => (w.h.p.) some dword violates that (e.g. 0x00003F80).
__global__ void probe_kernel(const void* __restrict__ adj, int* __restrict__ flag) {
    __shared__ int red[256];
    const int tid = threadIdx.x;
    const unsigned int* p = (const unsigned int*)adj;
    int ok = 1;
    for (int i = tid; i < 16384; i += 256) {
        const unsigned int d = p[i];
        ok &= (d == 0u || d == 0x3F800000u);
    }
    red[tid] = ok;
    __syncthreads();
    for (int s = 128; s > 0; s >>= 1) { if (tid < s) red[tid] &= red[tid + s]; __syncthreads(); }
    if (tid == 0) flag[0] = red[0];   // 1 => float32, 0 => bf16
}

// Kernel 1: precompute u = Wc@v, w2 = Wf@v, g = u + Wx@u, and scalar consts.
// consts[0]=bx.u ; consts[1]=beta*(bc.v)+bf.v+bs ; consts[2]=sign ; consts[3]=beta
__global__ void pre_kernel(const void* __restrict__ Wx, const void* __restrict__ bx,
                           const void* __restrict__ Wc, const void* __restrict__ bc,
                           const void* __restrict__ Wf, const void* __restrict__ bf_,
                           const void* __restrict__ v_, const void* __restrict__ bs,
                           const void* __restrict__ beta, const int* __restrict__ boolen,
                           const int* __restrict__ flag,
                           float* __restrict__ u, float* __restrict__ w2,
                           float* __restrict__ g, float* __restrict__ consts) {
    const int isf32 = flag[0];
    __shared__ float sv[Hh];
    __shared__ float su[Hh];
    __shared__ float red[Hh];
    const int k = threadIdx.x;
    sv[k] = ld(v_, k, isf32);
    __syncthreads();
    float uk = 0.f, w2k = 0.f;
    for (int j = 0; j < Hh; ++j) {
        uk  = fmaf(ld(Wc, k * Hh + j, isf32), sv[j], uk);
        w2k = fmaf(ld(Wf, k * Hh + j, isf32), sv[j], w2k);
    }
    su[k] = uk;
    __syncthreads();
    float gk = uk;
    for (int j = 0; j < Hh; ++j) gk = fmaf(ld(Wx, k * Hh + j, isf32), su[j], gk);
    u[k] = uk; w2[k] = w2k; g[k] = gk;

    // reduction 1: bc . v
    red[k] = ld(bc, k, isf32) * sv[k];
    __syncthreads();
    for (int s = 128; s > 0; s >>= 1) { if (k < s) red[k] += red[k + s]; __syncthreads(); }
    float bcv = red[0];
    __syncthreads();
    // reduction 2: bf . v
    red[k] = ld(bf_, k, isf32) * sv[k];
    __syncthreads();
    for (int s = 128; s > 0; s >>= 1) { if (k < s) red[k] += red[k + s]; __syncthreads(); }
    float bfv = red[0];
    __syncthreads();
    // reduction 3: bx . u
    red[k] = ld(bx, k, isf32) * su[k];
    __syncthreads();
    for (int s = 128; s > 0; s >>= 1) { if (k < s) red[k] += red[k + s]; __syncthreads(); }
    if (k == 0) {
        const float be = ld(beta, 0, isf32);
        consts[0] = red[0];
        consts[1] = be * bcv + bfv + ld(bs, 0, isf32);
        consts[2] = (boolen[0] != 0) ? 1.f : -1.f;
        consts[3] = be;
    }
}

// Kernel 2: t[n] = x[n] . g + c0
__global__ void t_kernel(const void* __restrict__ x, const float* __restrict__ g,
                         const float* __restrict__ consts, const int* __restrict__ flag,
                         float* __restrict__ t) {
    const int isf32 = flag[0];
    const int n = blockIdx.x;
    const int j = threadIdx.x;
    __shared__ float red[Hh];
    red[j] = ld(x, n * Hh + j, isf32) * g[j];
    __syncthreads();
    for (int s = 128; s > 0; s >>= 1) { if (j < s) red[j] += red[j + s]; __syncthreads(); }
    if (j == 0) t[n] = red[0] + consts[0];
}

// Kernel 3: P = x@Wi + bi, Q = x@Wj + bj  (fp32 out), 8 rows per block
__global__ void pq_kernel(const void* __restrict__ x,
                          const void* __restrict__ Wi, const void* __restrict__ Wj,
                          const void* __restrict__ bi, const void* __restrict__ bj,
                          const int* __restrict__ flag,
                          float* __restrict__ P, float* __restrict__ Q) {
    const int isf32 = flag[0];
    const int R = 8;
    __shared__ float xs[R][Hh];
    const int base = blockIdx.x * R;
    const int j = threadIdx.x;
    for (int r = 0; r < R; ++r) xs[r][j] = ld(x, (base + r) * Hh + j, isf32);
    __syncthreads();
    float accP[R], accQ[R];
    const float fbi = ld(bi, j, isf32), fbj = ld(bj, j, isf32);
#pragma unroll
    for (int r = 0; r < R; ++r) { accP[r] = fbi; accQ[r] = fbj; }
    for (int k = 0; k < Hh; ++k) {
        const float wi = ld(Wi, k * Hh + j, isf32);
        const float wj = ld(Wj, k * Hh + j, isf32);
#pragma unroll
        for (int r = 0; r < R; ++r) {
            accP[r] = fmaf(xs[r][k], wi, accP[r]);
            accQ[r] = fmaf(xs[r][k], wj, accQ[r]);
        }
    }
    for (int r = 0; r < R; ++r) {
        P[(size_t)(base + r) * Hh + j] = accP[r];
        Q[(size_t)(base + r) * Hh + j] = accQ[r];
    }
}

// Kernel 4: per-edge block. s_cn = sum_n adj[src,n]*adj[dst,n]*t[n];
// s_ij = sum_j relu(P[src,j]+Q[dst,j])*w2[j]; out = softplus(-sign*(beta*s_cn + s_ij + c1))
__global__ void edge_kernel(const void* __restrict__ adj, const int* __restrict__ tei,
                            const float* __restrict__ P, const float* __restrict__ Q,
                            const float* __restrict__ w2, const float* __restrict__ t,
                            const float* __restrict__ consts, const int* __restrict__ flag,
                            void* __restrict__ out) {
    const int isf32 = flag[0];
    const int e = blockIdx.x;
    const int tid = threadIdx.x;
    const int src = tei[e];
    const int dst = tei[Ee + e];
    float accA = 0.f;
    if (isf32) {
        const float* rowS = (const float*)adj + (size_t)src * Nn;
        const float* rowD = (const float*)adj + (size_t)dst * Nn;
#pragma unroll
        for (int it = 0; it < 8; ++it) {
            const int idx = it * 1024 + tid * 4;
            const float4 a = *reinterpret_cast<const float4*>(rowS + idx);
            const float4 b = *reinterpret_cast<const float4*>(rowD + idx);
            accA = fmaf(a.x * b.x, t[idx + 0], accA);
            accA = fmaf(a.y * b.y, t[idx + 1], accA);
            accA = fmaf(a.z * b.z, t[idx + 2], accA);
            accA = fmaf(a.w * b.w, t[idx + 3], accA);
        }
    } else {
        const bf16* rowS = (const bf16*)adj + (size_t)src * Nn;
        const bf16* rowD = (const bf16*)adj + (size_t)dst * Nn;
#pragma unroll
        for (int it = 0; it < 4; ++it) {
            const int idx = it * 2048 + tid * 8;
            const uint4 pa = *reinterpret_cast<const uint4*>(rowS + idx);
            const uint4 pb = *reinterpret_cast<const uint4*>(rowD + idx);
            const unsigned int ua[4] = {pa.x, pa.y, pa.z, pa.w};
            const unsigned int ub[4] = {pb.x, pb.y, pb.z, pb.w};
#pragma unroll
            for (int q = 0; q < 4; ++q) {
                const float a0 = us2f(ua[q] & 0xffffu);
                const float a1 = us2f(ua[q] >> 16);
                const float b0 = us2f(ub[q] & 0xffffu);
                const float b1 = us2f(ub[q] >> 16);
                accA = fmaf(a0 * b0, t[idx + 2 * q], accA);
                accA = fmaf(a1 * b1, t[idx + 2 * q + 1], accA);
            }
        }
    }
    const float r = P[(size_t)src * Hh + tid] + Q[(size_t)dst * Hh + tid];
    const float accB = (r > 0.f) ? r * w2[tid] : 0.f;

    __shared__ float redA[Hh];
    __shared__ float redB[Hh];
    redA[tid] = accA;
    redB[tid] = accB;
    __syncthreads();
    for (int s = 128; s > 0; s >>= 1) {
        if (tid < s) { redA[tid] += redA[tid + s]; redB[tid] += redB[tid + s]; }
        __syncthreads();
    }
    if (tid == 0) {
        const float be = consts[3];
        const float sgn = consts[2];
        const float s = be * redA[0] + redB[0] + consts[1];
        const float m = -sgn * s;
        const float res = fmaxf(m, 0.f) + log1pf(expf(-fabsf(m)));
        if (isf32) ((float*)out)[e] = res;
        else       ((bf16*)out)[e] = __float2bfloat16(res);
    }
}

extern "C" void kernel_launch(void* const* d_in, const int* in_sizes, int n_in,
                              void* d_out, int out_size, void* d_ws, size_t ws_size,
                              hipStream_t stream) {
    const void* x     = d_in[0];
    const void* adj   = d_in[1];
    const int*  tei   = (const int*)d_in[2];
    const void* Wx    = d_in[3];
    const void* bx    = d_in[4];
    const void* Wc    = d_in[5];
    const void* bc    = d_in[6];
    const void* Wi    = d_in[7];
    const void* bi    = d_in[8];
    const void* Wj    = d_in[9];
    const void* bj    = d_in[10];
    const void* Wf    = d_in[11];
    const void* bf_   = d_in[12];
    const void* v_    = d_in[13];
    const void* bs    = d_in[14];
    const void* beta  = d_in[15];
    const int*  booln = (const int*)d_in[16];

    // workspace layout (fp32 elements after the int flag):
    int*   flag   = (int*)d_ws;                  // 4 slots (16B align)
    float* u      = (float*)d_ws + 4;            // 256
    float* w2     = u + 256;                     // 256
    float* g      = w2 + 256;                    // 256
    float* consts = g + 256;                     // 8 (padded)
    float* t      = consts + 8;                  // 8192
    float* P      = t + 8192;                    // 8192*256
    float* Q      = P + (size_t)8192 * 256;      // 8192*256
    // total ≈ 16.8 MB < ws_size (assumed)

    probe_kernel<<<1, 256, 0, stream>>>(adj, flag);
    pre_kernel<<<1, 256, 0, stream>>>(Wx, bx, Wc, bc, Wf, bf_, v_, bs, beta, booln,
                                      flag, u, w2, g, consts);
    t_kernel<<<Nn, 256, 0, stream>>>(x, g, consts, flag, t);
    pq_kernel<<<Nn / 8, 256, 0, stream>>>(x, Wi, Wj, bi, bj, flag, P, Q);
    edge_kernel<<<Ee, 256, 0, stream>>>(adj, tei, P, Q, w2, t, consts, flag, (void*)d_out);
}

// Round 4
// 566.159 us; speedup vs baseline: 1.0730x; 1.0730x over previous
//
#include <hip/hip_runtime.h>
#include <hip/hip_bf16.h>

#define Nn 8192
#define Ee 8192
#define Hh 256
#define MASK_W 128   // 8192 bits / 64

typedef unsigned long long u64;

// ---------------------------------------------------------------------------
// Kernel 1: tiny precompute. u = Wc@v, w2 = Wf@v, g = u + Wx@u, scalar consts.
// consts[0]=bx.u ; consts[1]=beta*(bc.v)+bf.v+bs ; consts[2]=sign ; consts[3]=beta
// ---------------------------------------------------------------------------
__global__ void pre_kernel(const float* __restrict__ Wx, const float* __restrict__ bx,
                           const float* __restrict__ Wc, const float* __restrict__ bc,
                           const float* __restrict__ Wf, const float* __restrict__ bf_,
                           const float* __restrict__ v_, const float* __restrict__ bs,
                           const float* __restrict__ beta, const int* __restrict__ boolen,
                           float* __restrict__ u, float* __restrict__ w2,
                           float* __restrict__ g, float* __restrict__ consts) {
    __shared__ float sv[Hh];
    __shared__ float su[Hh];
    __shared__ float red[Hh];
    const int k = threadIdx.x;
    sv[k] = v_[k];
    __syncthreads();
    float uk = 0.f, w2k = 0.f;
    for (int j = 0; j < Hh; ++j) {
        uk  = fmaf(Wc[k * Hh + j], sv[j], uk);
        w2k = fmaf(Wf[k * Hh + j], sv[j], w2k);
    }
    su[k] = uk;
    __syncthreads();
    float gk = uk;
    for (int j = 0; j < Hh; ++j) gk = fmaf(Wx[k * Hh + j], su[j], gk);
    u[k] = uk; w2[k] = w2k; g[k] = gk;

    red[k] = bc[k] * sv[k];
    __syncthreads();
    for (int s = 128; s > 0; s >>= 1) { if (k < s) red[k] += red[k + s]; __syncthreads(); }
    const float bcv = red[0];
    __syncthreads();
    red[k] = bf_[k] * sv[k];
    __syncthreads();
    for (int s = 128; s > 0; s >>= 1) { if (k < s) red[k] += red[k + s]; __syncthreads(); }
    const float bfv = red[0];
    __syncthreads();
    red[k] = bx[k] * su[k];
    __syncthreads();
    for (int s = 128; s > 0; s >>= 1) { if (k < s) red[k] += red[k + s]; __syncthreads(); }
    if (k == 0) {
        const float be = beta[0];
        consts[0] = red[0];
        consts[1] = be * bcv + bfv + bs[0];
        consts[2] = (boolen[0] != 0) ? 1.f : -1.f;
        consts[3] = be;
    }
}

// ---------------------------------------------------------------------------
// Kernel 2: bit-pack adj (f32 0/1) into u64 masks. One thread -> one u64.
// mask[row][col] bit b  <=>  adj[row][col*64+b] != 0
// ---------------------------------------------------------------------------
__global__ void pack_kernel(const float* __restrict__ adj, u64* __restrict__ mask) {
    const int gid = blockIdx.x * blockDim.x + threadIdx.x;   // 0 .. 8192*128-1
    const int row = gid >> 7;
    const int col = gid & 127;
    const float4* p = reinterpret_cast<const float4*>(adj + (size_t)row * Nn + col * 64);
    u64 m = 0;
#pragma unroll
    for (int q = 0; q < 16; ++q) {
        const float4 v = p[q];
        if (v.x != 0.f) m |= 1ull << (q * 4 + 0);
        if (v.y != 0.f) m |= 1ull << (q * 4 + 1);
        if (v.z != 0.f) m |= 1ull << (q * 4 + 2);
        if (v.w != 0.f) m |= 1ull << (q * 4 + 3);
    }
    mask[gid] = m;
}

// ---------------------------------------------------------------------------
// Kernel 3: P = x@Wi + bi, Q = x@Wj + bj (fp32), plus t[n] = x[n].g + c0.
// 16 rows/block; x staged in LDS; weights read per-k (lane-coalesced, L2-hot).
// ---------------------------------------------------------------------------
#define RQ 16
__global__ void __launch_bounds__(256)
pq_kernel(const float* __restrict__ x,
          const float* __restrict__ Wi, const float* __restrict__ Wj,
          const float* __restrict__ bi, const float* __restrict__ bj,
          const float* __restrict__ g, const float* __restrict__ consts,
          float* __restrict__ P, float* __restrict__ Q, float* __restrict__ t) {
    __shared__ float xs[RQ][Hh];                 // 16 KB
    const int tid = threadIdx.x;
    const int base = blockIdx.x * RQ;

    // stage x rows: RQ*Hh = 4096 floats = 1024 float4
    {
        const float4* xv = reinterpret_cast<const float4*>(x + (size_t)base * Hh);
        float4* xd = reinterpret_cast<float4*>(&xs[0][0]);
#pragma unroll
        for (int i = tid; i < 1024; i += 256) xd[i] = xv[i];
    }
    __syncthreads();

    // t for this block's rows: wave w handles rows 4w..4w+3
    {
        const int wave = tid >> 6;
        const int lane = tid & 63;
        const float c0 = consts[0];
#pragma unroll
        for (int r0 = 0; r0 < 4; ++r0) {
            const int r = wave * 4 + r0;
            float s = 0.f;
#pragma unroll
            for (int i = 0; i < 4; ++i) {
                const int c = lane * 4 + i;
                s = fmaf(xs[r][c], g[c], s);
            }
            for (int off = 32; off > 0; off >>= 1) s += __shfl_down(s, off);
            if (lane == 0) t[base + r] = s + c0;
        }
    }

    float accP[RQ], accQ[RQ];
    const float fbi = bi[tid], fbj = bj[tid];
#pragma unroll
    for (int r = 0; r < RQ; ++r) { accP[r] = fbi; accQ[r] = fbj; }

#pragma unroll 4
    for (int k = 0; k < Hh; ++k) {
        const float wiv = Wi[k * Hh + tid];
        const float wjv = Wj[k * Hh + tid];
#pragma unroll
        for (int r = 0; r < RQ; ++r) {
            accP[r] = fmaf(xs[r][k], wiv, accP[r]);
            accQ[r] = fmaf(xs[r][k], wjv, accQ[r]);
        }
    }
#pragma unroll
    for (int r = 0; r < RQ; ++r) {
        P[(size_t)(base + r) * Hh + tid] = accP[r];
        Q[(size_t)(base + r) * Hh + tid] = accQ[r];
    }
}

// ---------------------------------------------------------------------------
// Kernel 4: per-edge block.
// accA = sum over common-neighbor bits of t[n]; accB = relu(P[src]+Q[dst]).w2
// out = softplus(-sign*(beta*accA + accB + c1))
// ---------------------------------------------------------------------------
__global__ void edge_kernel(const u64* __restrict__ mask, const int* __restrict__ tei,
                            const float* __restrict__ P, const float* __restrict__ Q,
                            const float* __restrict__ w2, const float* __restrict__ t,
                            const float* __restrict__ consts, float* __restrict__ out) {
    const int e = blockIdx.x;
    const int tid = threadIdx.x;
    const int src = tei[e];
    const int dst = tei[Ee + e];

    __shared__ u64 ms[MASK_W];
    __shared__ u64 md[MASK_W];
    if (tid < MASK_W) ms[tid] = mask[(size_t)src * MASK_W + tid];
    else              md[tid - MASK_W] = mask[(size_t)dst * MASK_W + (tid - MASK_W)];
    __syncthreads();

    float accA = 0.f;
    if (tid < MASK_W) {
        u64 m = ms[tid] & md[tid];
        while (m) {
            const int b = __builtin_ctzll(m);
            accA += t[tid * 64 + b];
            m &= m - 1;
        }
    }
    const float r = P[(size_t)src * Hh + tid] + Q[(size_t)dst * Hh + tid];
    float accB = (r > 0.f) ? r * w2[tid] : 0.f;

    for (int off = 32; off > 0; off >>= 1) {
        accA += __shfl_down(accA, off);
        accB += __shfl_down(accB, off);
    }
    __shared__ float wA[4], wB[4];
    const int wave = tid >> 6;
    if ((tid & 63) == 0) { wA[wave] = accA; wB[wave] = accB; }
    __syncthreads();
    if (tid == 0) {
        const float sA = wA[0] + wA[1] + wA[2] + wA[3];
        const float sB = wB[0] + wB[1] + wB[2] + wB[3];
        const float be = consts[3];
        const float sgn = consts[2];
        const float s = be * sA + sB + consts[1];
        const float m = -sgn * s;
        const float res = fmaxf(m, 0.f) + log1pf(expf(-fabsf(m)));
        out[e] = res;
    }
}

extern "C" void kernel_launch(void* const* d_in, const int* in_sizes, int n_in,
                              void* d_out, int out_size, void* d_ws, size_t ws_size,
                              hipStream_t stream) {
    const float* x     = (const float*)d_in[0];
    const float* adj   = (const float*)d_in[1];
    const int*   tei   = (const int*)d_in[2];
    const float* Wx    = (const float*)d_in[3];
    const float* bx    = (const float*)d_in[4];
    const float* Wc    = (const float*)d_in[5];
    const float* bc    = (const float*)d_in[6];
    const float* Wi    = (const float*)d_in[7];
    const float* bi    = (const float*)d_in[8];
    const float* Wj    = (const float*)d_in[9];
    const float* bj    = (const float*)d_in[10];
    const float* Wf    = (const float*)d_in[11];
    const float* bf_   = (const float*)d_in[12];
    const float* v_    = (const float*)d_in[13];
    const float* bs    = (const float*)d_in[14];
    const float* beta  = (const float*)d_in[15];
    const int*   booln = (const int*)d_in[16];
    float* out = (float*)d_out;

    // workspace layout (fp32 elements)
    float* u      = (float*)d_ws;                // 256
    float* w2     = u + 256;                     // 256
    float* g      = w2 + 256;                    // 256
    float* consts = g + 256;                     // 8 (padded)
    float* t      = consts + 8;                  // 8192
    float* P      = t + 8192;                    // 8192*256 = 8 MB
    float* Q      = P + (size_t)Nn * Hh;         // 8 MB
    u64*   mask   = (u64*)(Q + (size_t)Nn * Hh); // 8192*128 u64 = 8 MB
    // total ~25 MB << ws_size

    pack_kernel<<<(Nn * MASK_W) / 256, 256, 0, stream>>>(adj, mask);
    pre_kernel<<<1, 256, 0, stream>>>(Wx, bx, Wc, bc, Wf, bf_, v_, bs, beta, booln,
                                      u, w2, g, consts);
    pq_kernel<<<Nn / RQ, 256, 0, stream>>>(x, Wi, Wj, bi, bj, g, consts, P, Q, t);
    edge_kernel<<<Ee, 256, 0, stream>>>(mask, tei, P, Q, w2, t, consts, out);
}